// Round 18
// baseline (27.887 us; speedup 1.0000x reference)
//
#include <hip/hip_runtime.h>
#include <hip/hip_bf16.h>

// HalfKP input layer, king-grouped MFMA, phase-overlapped:
//   per king k: D = A_k (n_k x 672 bf16 0/1) x W_k (672x256 -> bf16)
//   out[b,c] = bias[c] + D[entry(b,0)] + D[entry(b,1)]
// B=1024, K=64, F=640(+row 640), C=256. W is (64,641,256) fp32 = 42 MB.
//
// R18 vs R17: five structures all ~27us; dispatch gaps proven ~0 (R14 vs
// R15). Remaining lever: the mask phase + a barrier sit AFTER staging lands.
// Reorder: issue stage loads -> list build -> chunk-0 mask build (runs under
// HBM latency) -> pack+ds_write -> ONE barrier -> MFMA. WPAD 20->17 (-4KB
// LDS; banks j*17%32 = {0,17,2,19} distinct = conflict-free). Rest verbatim
// R17 (absmax 0.5).

#define F_DIM 640
#define C_DIM 256
#define SLAB_STRIDE (641 * 256)   // floats per king slab
#define NKING 64
#define LCAP 256                  // list capacity per king
#define NC_MAX 64                 // max 64-entry chunks (nent <= 4096)
#define WPAD 17                   // LDS row stride in u32 (16 used + 1 pad)

// ws layout (bytes)
#define WS_MASK_OFF 0                        // 1024*10*8 = 80 KB
#define WS_PART_OFF 81920                    // 2*1024*256*4 = 2 MB
#define WS_NEED (WS_PART_OFF + 2 * 1024 * 256 * 4)

typedef float  f32x4  __attribute__((ext_vector_type(4)));
typedef short  bf16x8 __attribute__((ext_vector_type(8)));

__device__ __forceinline__ unsigned f2bf_pk(float a, float b) {
    // two RNE fp32->bf16, packed lo|hi (bit-exact, HW-verified R8-R17)
    union { float f; unsigned u; } x, y;
    x.f = a; y.f = b;
    const unsigned ra = (x.u + 0x7FFFu + ((x.u >> 16) & 1u)) >> 16;
    const unsigned rb = (y.u + 0x7FFFu + ((y.u >> 16) & 1u)) >> 16;
    return (ra & 0xFFFFu) | (rb << 16);
}

__device__ __forceinline__ bf16x8 mk_a8(unsigned m32, int g) {
    // A-frag: 8 bf16 0/1 from byte g of a 32-bit window mask (k = g*8 + j)
    const unsigned by = (m32 >> (g * 8)) & 0xFFu;
    union { unsigned u[4]; bf16x8 v; } r;
    #pragma unroll
    for (int i = 0; i < 4; ++i)
        r.u[i] = (((by >> (2 * i)) & 1u) ? 0x3F80u : 0u) |
                 (((by >> (2 * i + 1)) & 1u) ? 0x3F800000u : 0u);
    return r.v;
}

__global__ __launch_bounds__(256)
void pack_masks(const int* __restrict__ pieces,          // (B,640) int32 0/1
                unsigned long long* __restrict__ mask,   // (B,10)
                int nwords)                              // B*10
{
    const int gw = blockIdx.x * 4 + (threadIdx.x >> 6);
    const int lane = threadIdx.x & 63;
    if (gw >= nwords) return;
    const int v = pieces[(size_t)gw * 64 + lane];
    const unsigned long long m = __ballot(v != 0);
    if (lane == 0) mask[gw] = m;
}

__global__ __launch_bounds__(512, 8)
void halfkp_mfma(const float* __restrict__ W,                 // (64,641,256)
                 const unsigned long long* __restrict__ mask, // (B,10)
                 const int* __restrict__ kings,               // flat (B*2)
                 float* __restrict__ partial,                 // (2,B,256)
                 int nent)
{
    const int k  = blockIdx.x;
    const int cq = blockIdx.y;               // 0..15, 16 cols each
    const int t  = threadIdx.x;
    const int wv = t >> 6, lane = t & 63;
    const int mt = wv & 1;                   // M-tile slot 0..1
    const int kh = wv >> 1;                  // K-quarter 0..3
    const int li = lane & 15, g = lane >> 4;
    const int colG = cq * 16 + li;

    __shared__ unsigned s_W[336 * WPAD];     // 22.3 KB bf16-pair x 16 cols
    __shared__ int s_ent[LCAP];
    __shared__ int s_cb[NC_MAX + 1];
    __shared__ unsigned s_m32[64][21];       // all rows' window masks (5.25 KB)
    __shared__ f32x4 s_red[4][64];           // 4 KB fixed-tree reduce
    __shared__ int s_nk;

    // ---- A: issue W staging loads (6 float4 in flight, 24 VGPR) ----
    const float* __restrict__ Wq = W + (size_t)k * SLAB_STRIDE + cq * 16;
    float4 ve[3], vo[3];
    #pragma unroll
    for (int it = 0; it < 3; ++it) {
        const int task = t + (it << 9);      // 1344 tasks = 336 fp x 4 c4
        if (task < 336 * 4) {
            const int fp = task >> 2, c4 = task & 3;
            const int fe = min(2 * fp, F_DIM);
            const int fo = min(2 * fp + 1, F_DIM);
            ve[it] = *(const float4*)&Wq[(size_t)fe * C_DIM + c4 * 4];
            vo[it] = *(const float4*)&Wq[(size_t)fo * C_DIM + c4 * 4];
        }
    }

    // ---- B: in-block list build (R10-verified), overlaps staging latency ----
    {
        const int NC = nent >> 6;            // 64-entry chunks
        const int nit = NC >> 3;             // chunks per wave (8 waves)
        unsigned long long mm[8];
        #pragma unroll
        for (int it = 0; it < 8; ++it) {
            if (it < nit) {
                const int c = wv + (it << 3);
                const int kk = kings[(c << 6) + lane];
                mm[it] = __ballot(kk == k);
                if (lane == 0) s_cb[c] = (int)__popcll(mm[it]);
            }
        }
        __syncthreads();
        if (t == 0) {
            int s = 0;
            for (int c = 0; c < NC; ++c) { const int v = s_cb[c]; s_cb[c] = s; s += v; }
            s_nk = min(s, LCAP);
        }
        __syncthreads();
        const unsigned long long lt = (1ull << lane) - 1ull;
        #pragma unroll
        for (int it = 0; it < 8; ++it) {
            if (it < nit) {
                const int c = wv + (it << 3);
                if ((mm[it] >> lane) & 1ull) {
                    const int pos = s_cb[c] + (int)__popcll(mm[it] & lt);
                    if (pos < LCAP) s_ent[pos] = (c << 6) + lane;
                }
            }
        }
    }
    __syncthreads();                          // s_ent/s_nk ready
    const int n_k = s_nk;

    // ---- B2: chunk-0 mask build (still under staging-load latency) ----
    {
        const int ncc0 = min(n_k, 64);
        for (int idx = t; idx < 64 * 21; idx += 512) {
            const int row = idx & 63, ks = idx >> 6;
            const int id = (row < ncc0) ? s_ent[row] : -1;
            unsigned v = 0;
            if (id >= 0) {
                if (ks < 20) {
                    const unsigned long long mw = mask[(size_t)(id >> 1) * 10 + (ks >> 1)];
                    v = (unsigned)(mw >> ((ks & 1) * 32));
                } else {
                    v = 1u;                  // always-active row 640
                }
            }
            s_m32[row][ks] = v;
        }
    }

    // ---- C: pack staged W and write to LDS (ds_write_b128) ----
    #pragma unroll
    for (int it = 0; it < 3; ++it) {
        const int task = t + (it << 9);
        if (task < 336 * 4) {
            const int fp = task >> 2, c4 = task & 3;
            union { unsigned u[4]; f32x4 v; } pk;
            pk.u[0] = f2bf_pk(ve[it].x, vo[it].x);
            pk.u[1] = f2bf_pk(ve[it].y, vo[it].y);
            pk.u[2] = f2bf_pk(ve[it].z, vo[it].z);
            pk.u[3] = f2bf_pk(ve[it].w, vo[it].w);
            *(f32x4*)&s_W[fp * WPAD + c4 * 4] = pk.v;
        }
    }
    __syncthreads();                          // single barrier: s_W + s_m32 ready

    for (int mb = 0; mb < n_k; mb += 64) {    // realistically one iteration
        const int ncc = min(n_k - mb, 64);

        if (mb > 0) {                         // rare: rebuild masks inline
            __syncthreads();
            for (int idx = t; idx < 64 * 21; idx += 512) {
                const int row = idx & 63, ks = idx >> 6;
                const int id = (row < ncc) ? s_ent[mb + row] : -1;
                unsigned v = 0;
                if (id >= 0) {
                    if (ks < 20) {
                        const unsigned long long mw = mask[(size_t)(id >> 1) * 10 + (ks >> 1)];
                        v = (unsigned)(mw >> ((ks & 1) * 32));
                    } else {
                        v = 1u;
                    }
                }
                s_m32[row][ks] = v;
            }
            __syncthreads();
        }

        const int ntiles = (ncc + 15) >> 4;   // <= 4
        const int ks_beg = (kh == 0) ? 0 : (kh == 1) ? 6 : (kh == 2) ? 11 : 16;
        const int ks_end = (kh == 0) ? 6 : (kh == 1) ? 11 : (kh == 2) ? 16 : 21;

        for (int tb = 0; tb < ntiles; tb += 2) {
            const int tile = tb + mt;
            const bool live = tile * 16 < ncc;
            f32x4 acc = {0.f, 0.f, 0.f, 0.f};
            if (live) {
                const unsigned* mrow = s_m32[tile * 16 + li];
                #pragma unroll 2
                for (int ks = ks_beg; ks < ks_end; ++ks) {
                    const unsigned* bp = &s_W[(ks * 16 + g * 4) * WPAD + li];
                    union { unsigned u[4]; bf16x8 v; } bb;
                    #pragma unroll
                    for (int jj = 0; jj < 4; ++jj)
                        bb.u[jj] = bp[jj * WPAD];
                    const bf16x8 af = mk_a8(mrow[ks], g);
                    acc = __builtin_amdgcn_mfma_f32_16x16x32_bf16(af, bb.v, acc, 0, 0, 0);
                }
                if (kh >= 2) s_red[mt * 2 + kh - 2][lane] = acc;
            }
            __syncthreads();
            if (live && kh < 2) {
                acc += s_red[mt * 2 + kh][lane];     // kh0+=kh2, kh1+=kh3
                if (kh == 1) s_red[mt * 2][lane] = acc;
            }
            __syncthreads();
            if (live && kh == 0) {
                acc += s_red[mt * 2][lane];          // (kh0+kh2)+(kh1+kh3)
                // D: reg i -> row = tile*16 + 4*g + i, col = colG (m89-verified)
                #pragma unroll
                for (int i = 0; i < 4; ++i) {
                    const int r = tile * 16 + 4 * g + i;
                    if (r < ncc) {
                        const int id = s_ent[mb + r];
                        partial[(((size_t)(id & 1)) * 1024 + (id >> 1)) * C_DIM + colG] = acc[i];
                    }
                }
            }
            __syncthreads();   // protect s_red before next tile pass
        }
    }
}

__global__ __launch_bounds__(256)
void finalize(const float* __restrict__ partial,
              const float* __restrict__ bias,
              float* __restrict__ out)
{
    const int i = blockIdx.x * 256 + threadIdx.x;    // float4 index, B*64 total
    const float4 b4 = ((const float4*)bias)[i & 63];
    const float4 p0 = ((const float4*)partial)[i];
    const float4 p1 = ((const float4*)partial)[1024 * 64 + i];
    float4 o;
    o.x = b4.x + p0.x + p1.x;
    o.y = b4.y + p0.y + p1.y;
    o.z = b4.z + p0.z + p1.z;
    o.w = b4.w + p0.w + p1.w;
    ((float4*)out)[i] = o;
}

// ---- fallback (R3 path) if ws is too small ----
__global__ __launch_bounds__(256)
void halfkp_fallback(const int* __restrict__ pieces, const int* __restrict__ kings,
                     const float* __restrict__ W, const float* __restrict__ bias,
                     float* __restrict__ out)
{
    const int b = blockIdx.x;
    const int c = threadIdx.x;
    const int lane = c & 63;
    const int k0 = kings[2 * b + 0];
    const int k1 = kings[2 * b + 1];
    const float* W0 = W + (size_t)k0 * SLAB_STRIDE + c;
    const float* W1 = W + (size_t)k1 * SLAB_STRIDE + c;
    float acc = bias[c] + W0[640 * 256] + W1[640 * 256];
    const int* pi = pieces + (size_t)b * F_DIM;
    #pragma unroll
    for (int ch = 0; ch < 10; ++ch) {
        int v = pi[ch * 64 + lane];
        unsigned long long m = __ballot(v != 0);
        const float* b0 = W0 + ch * 64 * 256;
        const float* b1 = W1 + ch * 64 * 256;
        while (m) {
            const int f = __builtin_ctzll(m);
            m &= m - 1;
            acc += b0[f * 256] + b1[f * 256];
        }
    }
    out[(size_t)b * C_DIM + c] = acc;
}

extern "C" void kernel_launch(void* const* d_in, const int* in_sizes, int n_in,
                              void* d_out, int out_size, void* d_ws, size_t ws_size,
                              hipStream_t stream) {
    const int* pieces = (const int*)d_in[0];   // (1024, 640) int32 bools
    const int* kings  = (const int*)d_in[1];   // (1024, 2) int32
    const float* W    = (const float*)d_in[2]; // (64, 641, 256) f32
    const float* bias = (const float*)d_in[3]; // (256,) f32
    float* out        = (float*)d_out;         // (1024, 256) f32

    const int B = in_sizes[1] / 2;             // 1024
    const int nent = 2 * B;
    const int nwords = B * 10;

    if (ws_size < (size_t)WS_NEED) {
        halfkp_fallback<<<dim3(B), dim3(C_DIM), 0, stream>>>(pieces, kings, W, bias, out);
        return;
    }

    unsigned long long* mask = (unsigned long long*)((char*)d_ws + WS_MASK_OFF);
    float* part = (float*)((char*)d_ws + WS_PART_OFF);

    pack_masks<<<dim3((nwords + 3) / 4), dim3(256), 0, stream>>>(pieces, mask, nwords);
    halfkp_mfma<<<dim3(NKING, 16), dim3(512), 0, stream>>>(W, mask, kings, part, nent);
    finalize<<<dim3(B * 64 / 256), dim3(256), 0, stream>>>(part, bias, out);
}

// Round 19
// 27.866 us; speedup vs baseline: 1.0007x; 1.0007x over previous
//
#include <hip/hip_runtime.h>
#include <hip/hip_bf16.h>

// HalfKP input layer, K-BAND sequential-read MFMA:
//   per (king k, band bd): block reads W rows [bd*96, bd*96+96) x 256 cols
//   CONTIGUOUSLY, computes band-partials for all of king k's entries.
//   out[b,c] = bias[c] + sum over 7 bands x 2 persp of partial + (bias once)
// B=1024, K=64, F=640(+row 640), C=256. W is (64,641,256) fp32 = 42 MB.
//
// R19 vs R9-R18: six structures all ~27us. Cross-round counter synthesis:
// FETCH rate is ~1.1 TB/s in EVERY kernel (R2: 145MB/131us; R4: 23MB/21us;
// R14-18 same) = scattered-demand-fill MSHR wall; sequential reads measure
// 6.3 TB/s (m13). Fix: band-blocks read W contiguously (1KB/wave-instr).
// Wave = (M-slot x col-group) owns its output across the band's 3 windows ->
// NO inter-wave reduce. 14 band-partial slots (14.7 MB, ws~268MB per the
// poison-fill evidence), finalize sums in fixed order (deterministic; all
// slots written, no memset). LDS stride 260 -> MFMA ds_reads 2-way (free).
// List build / masks / A-B-D mappings verbatim (HW-verified, absmax 0.5).

#define F_DIM 640
#define C_DIM 256
#define SLAB_STRIDE (641 * 256)   // floats per king slab
#define NKING 64
#define NBAND 7                   // 7 bands x 96 rows = 672 padded rows
#define WROWS 96
#define WPR 48                    // pair-rows per band
#define WSTR 260                  // LDS row stride (u32): 2-way banks on reads
#define LCAP 256                  // list capacity per king
#define NC_MAX 64                 // max 64-entry chunks (nent <= 4096)

// ws layout (bytes)
#define WS_MASK_OFF 0                        // 1024*10*8 = 80 KB
#define WS_PART_OFF 81920                    // 14*1024*256*4 = 14,680,064
#define WS_NEED (WS_PART_OFF + NBAND * 2 * 1024 * 256 * 4)

typedef float  f32x4  __attribute__((ext_vector_type(4)));
typedef short  bf16x8 __attribute__((ext_vector_type(8)));

__device__ __forceinline__ unsigned f2bf_pk(float a, float b) {
    // two RNE fp32->bf16, packed lo|hi (bit-exact, HW-verified R8-R18)
    union { float f; unsigned u; } x, y;
    x.f = a; y.f = b;
    const unsigned ra = (x.u + 0x7FFFu + ((x.u >> 16) & 1u)) >> 16;
    const unsigned rb = (y.u + 0x7FFFu + ((y.u >> 16) & 1u)) >> 16;
    return (ra & 0xFFFFu) | (rb << 16);
}

__device__ __forceinline__ bf16x8 mk_a8(unsigned m32, int g) {
    // A-frag: 8 bf16 0/1 from byte g of a 32-bit window mask (k = g*8 + j)
    const unsigned by = (m32 >> (g * 8)) & 0xFFu;
    union { unsigned u[4]; bf16x8 v; } r;
    #pragma unroll
    for (int i = 0; i < 4; ++i)
        r.u[i] = (((by >> (2 * i)) & 1u) ? 0x3F80u : 0u) |
                 (((by >> (2 * i + 1)) & 1u) ? 0x3F800000u : 0u);
    return r.v;
}

__global__ __launch_bounds__(256)
void pack_masks(const int* __restrict__ pieces,          // (B,640) int32 0/1
                unsigned long long* __restrict__ mask,   // (B,10)
                int nwords)                              // B*10
{
    const int gw = blockIdx.x * 4 + (threadIdx.x >> 6);
    const int lane = threadIdx.x & 63;
    if (gw >= nwords) return;
    const int v = pieces[(size_t)gw * 64 + lane];
    const unsigned long long m = __ballot(v != 0);
    if (lane == 0) mask[gw] = m;
}

__global__ __launch_bounds__(512, 4)
void halfkp_kband(const float* __restrict__ W,                 // (64,641,256)
                  const unsigned long long* __restrict__ mask, // (B,10)
                  const int* __restrict__ kings,               // flat (B*2)
                  float* __restrict__ partial,                 // (14,B,256)
                  int nent)
{
    const int k  = blockIdx.x;
    const int bd = blockIdx.y;               // band 0..6
    const int t  = threadIdx.x;
    const int wv = t >> 6, lane = t & 63;
    const int mt = wv & 1;                   // M-tile slot (tiles mt, mt+2)
    const int cg = wv >> 1;                  // col-group 0..3 (64 cols)
    const int li = lane & 15, g = lane >> 4;

    __shared__ unsigned s_W[WPR * WSTR];     // 48*260*4 = 49.9 KB
    __shared__ int s_ent[LCAP];
    __shared__ int s_cb[NC_MAX + 1];
    __shared__ unsigned s_m32[64][3];        // band's 3 window masks per row
    __shared__ int s_nk;

    // ---- A: issue contiguous staging loads (12 float4 in flight) ----
    // 3072 tasks = 48 pair-rows x 64 col-quads; per wave-instr: one full
    // 1KB row segment (64 lanes x 16B contiguous) -> sequential stream.
    const int r0 = bd * WROWS;
    const float* __restrict__ Wk = W + (size_t)k * SLAB_STRIDE;
    float4 ve[6], vo[6];
    #pragma unroll
    for (int it = 0; it < 6; ++it) {
        const int task = t + (it << 9);      // 6*512 = 3072 exact
        const int pr = task >> 6, c4 = task & 63;
        const int fe = min(r0 + 2 * pr, F_DIM);
        const int fo = min(r0 + 2 * pr + 1, F_DIM);
        ve[it] = *(const float4*)&Wk[(size_t)fe * C_DIM + c4 * 4];
        vo[it] = *(const float4*)&Wk[(size_t)fo * C_DIM + c4 * 4];
    }

    // ---- B: in-block list build (R10-verified stable compaction) ----
    {
        const int NC = nent >> 6;            // 64-entry chunks
        const int nit = NC >> 3;             // chunks per wave (8 waves)
        unsigned long long mm[8];
        #pragma unroll
        for (int it = 0; it < 8; ++it) {
            if (it < nit) {
                const int c = wv + (it << 3);
                const int kk = kings[(c << 6) + lane];
                mm[it] = __ballot(kk == k);
                if (lane == 0) s_cb[c] = (int)__popcll(mm[it]);
            }
        }
        __syncthreads();
        if (t == 0) {
            int s = 0;
            for (int c = 0; c < NC; ++c) { const int v = s_cb[c]; s_cb[c] = s; s += v; }
            s_nk = min(s, LCAP);
        }
        __syncthreads();
        const unsigned long long lt = (1ull << lane) - 1ull;
        #pragma unroll
        for (int it = 0; it < 8; ++it) {
            if (it < nit) {
                const int c = wv + (it << 3);
                if ((mm[it] >> lane) & 1ull) {
                    const int pos = s_cb[c] + (int)__popcll(mm[it] & lt);
                    if (pos < LCAP) s_ent[pos] = (c << 6) + lane;
                }
            }
        }
    }
    __syncthreads();
    const int n_k = s_nk;

    // ---- C: chunk-0 mask build (3 windows of this band) ----
    {
        const int ncc0 = min(n_k, 64);
        for (int idx = t; idx < 64 * 3; idx += 512) {
            const int row = idx & 63, ksl = idx >> 6;
            const int ksg = bd * 3 + ksl;    // global window 0..20
            const int id = (row < ncc0) ? s_ent[row] : -1;
            unsigned v = 0;
            if (id >= 0) {
                if (ksg < 20) {
                    const unsigned long long mw = mask[(size_t)(id >> 1) * 10 + (ksg >> 1)];
                    v = (unsigned)(mw >> ((ksg & 1) * 32));
                } else {
                    v = 1u;                  // window 20: only row 640 live
                }
            }
            s_m32[row][ksl] = v;
        }
    }

    // ---- D: pack staged W and write to LDS (ds_write_b128) ----
    #pragma unroll
    for (int it = 0; it < 6; ++it) {
        const int task = t + (it << 9);
        const int pr = task >> 6, c4 = task & 63;
        union { unsigned u[4]; f32x4 v; } pk;
        pk.u[0] = f2bf_pk(ve[it].x, vo[it].x);
        pk.u[1] = f2bf_pk(ve[it].y, vo[it].y);
        pk.u[2] = f2bf_pk(ve[it].z, vo[it].z);
        pk.u[3] = f2bf_pk(ve[it].w, vo[it].w);
        *(f32x4*)&s_W[pr * WSTR + c4 * 4] = pk.v;
    }
    __syncthreads();                          // s_W + s_m32 ready

    for (int mb = 0; mb < n_k; mb += 64) {    // realistically one iteration
        const int ncc = min(n_k - mb, 64);

        if (mb > 0) {                         // rare: rebuild masks
            __syncthreads();
            for (int idx = t; idx < 64 * 3; idx += 512) {
                const int row = idx & 63, ksl = idx >> 6;
                const int ksg = bd * 3 + ksl;
                const int id = (row < ncc) ? s_ent[mb + row] : -1;
                unsigned v = 0;
                if (id >= 0) {
                    if (ksg < 20) {
                        const unsigned long long mw = mask[(size_t)(id >> 1) * 10 + (ksg >> 1)];
                        v = (unsigned)(mw >> ((ksg & 1) * 32));
                    } else {
                        v = 1u;
                    }
                }
                s_m32[row][ksl] = v;
            }
            __syncthreads();
        }

        // ---- wave-private MFMA: tiles {mt, mt+2}, 4 N-tiles, 3 windows ----
        #pragma unroll
        for (int tb = 0; tb < 4; tb += 2) {
            const int tile = tb + mt;
            if (tile * 16 < ncc) {
                f32x4 acc[4];
                #pragma unroll
                for (int nt = 0; nt < 4; ++nt) acc[nt] = (f32x4){0.f, 0.f, 0.f, 0.f};
                const unsigned* mrow = s_m32[tile * 16 + li];
                #pragma unroll
                for (int ksl = 0; ksl < 3; ++ksl) {
                    const bf16x8 af = mk_a8(mrow[ksl], g);
                    #pragma unroll
                    for (int nt = 0; nt < 4; ++nt) {
                        const unsigned* bp =
                            &s_W[(ksl * 16 + g * 4) * WSTR + cg * 64 + nt * 16 + li];
                        union { unsigned u[4]; bf16x8 v; } bb;
                        bb.u[0] = bp[0];
                        bb.u[1] = bp[WSTR];
                        bb.u[2] = bp[2 * WSTR];
                        bb.u[3] = bp[3 * WSTR];
                        acc[nt] = __builtin_amdgcn_mfma_f32_16x16x32_bf16(af, bb.v, acc[nt], 0, 0, 0);
                    }
                }
                // D: reg i -> row = tile*16 + 4*g + i (m89-verified);
                // partial slot = (bd*2 + persp); col = cg*64 + nt*16 + li.
                #pragma unroll
                for (int i = 0; i < 4; ++i) {
                    const int r = tile * 16 + 4 * g + i;
                    if (r < ncc) {
                        const int id = s_ent[mb + r];
                        float* dst = &partial[(((size_t)(bd * 2 + (id & 1))) * 1024
                                              + (id >> 1)) * C_DIM + cg * 64];
                        #pragma unroll
                        for (int nt = 0; nt < 4; ++nt)
                            dst[nt * 16 + li] = acc[nt][i];
                    }
                }
            }
        }
    }
}

__global__ __launch_bounds__(256)
void finalize(const float* __restrict__ partial,   // (14,B,256)
              const float* __restrict__ bias,
              float* __restrict__ out)
{
    const int i = blockIdx.x * 256 + threadIdx.x;    // float4 index, B*64 total
    float4 s = ((const float4*)bias)[i & 63];
    #pragma unroll
    for (int sl = 0; sl < NBAND * 2; ++sl) {         // fixed order: deterministic
        const float4 p = ((const float4*)partial)[(size_t)sl * 1024 * 64 + i];
        s.x += p.x; s.y += p.y; s.z += p.z; s.w += p.w;
    }
    ((float4*)out)[i] = s;
}

// ---- fallback (R3 path) if ws is too small ----
__global__ __launch_bounds__(256)
void halfkp_fallback(const int* __restrict__ pieces, const int* __restrict__ kings,
                     const float* __restrict__ W, const float* __restrict__ bias,
                     float* __restrict__ out)
{
    const int b = blockIdx.x;
    const int c = threadIdx.x;
    const int lane = c & 63;
    const int k0 = kings[2 * b + 0];
    const int k1 = kings[2 * b + 1];
    const float* W0 = W + (size_t)k0 * SLAB_STRIDE + c;
    const float* W1 = W + (size_t)k1 * SLAB_STRIDE + c;
    float acc = bias[c] + W0[640 * 256] + W1[640 * 256];
    const int* pi = pieces + (size_t)b * F_DIM;
    #pragma unroll
    for (int ch = 0; ch < 10; ++ch) {
        int v = pi[ch * 64 + lane];
        unsigned long long m = __ballot(v != 0);
        const float* b0 = W0 + ch * 64 * 256;
        const float* b1 = W1 + ch * 64 * 256;
        while (m) {
            const int f = __builtin_ctzll(m);
            m &= m - 1;
            acc += b0[f * 256] + b1[f * 256];
        }
    }
    out[(size_t)b * C_DIM + c] = acc;
}

extern "C" void kernel_launch(void* const* d_in, const int* in_sizes, int n_in,
                              void* d_out, int out_size, void* d_ws, size_t ws_size,
                              hipStream_t stream) {
    const int* pieces = (const int*)d_in[0];   // (1024, 640) int32 bools
    const int* kings  = (const int*)d_in[1];   // (1024, 2) int32
    const float* W    = (const float*)d_in[2]; // (64, 641, 256) f32
    const float* bias = (const float*)d_in[3]; // (256,) f32
    float* out        = (float*)d_out;         // (1024, 256) f32

    const int B = in_sizes[1] / 2;             // 1024
    const int nent = 2 * B;
    const int nwords = B * 10;

    if (ws_size < (size_t)WS_NEED) {
        halfkp_fallback<<<dim3(B), dim3(C_DIM), 0, stream>>>(pieces, kings, W, bias, out);
        return;
    }

    unsigned long long* mask = (unsigned long long*)((char*)d_ws + WS_MASK_OFF);
    float* part = (float*)((char*)d_ws + WS_PART_OFF);

    pack_masks<<<dim3((nwords + 3) / 4), dim3(256), 0, stream>>>(pieces, mask, nwords);
    halfkp_kband<<<dim3(NKING, NBAND), dim3(512), 0, stream>>>(W, mask, kings, part, nent);
    finalize<<<dim3(B * 64 / 256), dim3(256), 0, stream>>>(part, bias, out);
}

// Round 20
// 26.719 us; speedup vs baseline: 1.0437x; 1.0429x over previous
//
#include <hip/hip_runtime.h>
#include <hip/hip_bf16.h>

// HalfKP input layer, K-band MFMA with global_load_lds DMA staging:
//   per (king k, band bd): DMA rows [bd*96,+96) x 256 cols of W_k into LDS
//   (f32, 3 sub-windows of 32 rows), MFMA with on-the-fly bf16 cvt.
//   out[b,c] = bias[c] + sum over 7 bands x 2 persp of partial
// B=1024, K=64, F=640(+row 640), C=256. W is (64,641,256) fp32 = 42 MB.
//
// R20 vs R13-R19: all staging variants used global->VGPR->pack->ds_write;
// R13's counters proved that path serializes (637 GB/s). This round: pure
// DMA staging via __builtin_amdgcn_global_load_lds width=16 (Common-mistake
// #1; +67% lever at m193) - no VGPR round-trip. Global source pre-swizzled
// (lane ^= ((row>>3)&3)<<2, m173 pattern) so MFMA-phase ds_reads are 2-way
// banked (free); algebra: LDS[r*256 + (c^(g<<4))] == W[r][c]. bf16 cvt moves
// to read path (v_cvt_pk_bf16_f32, R12-verified). Rows>640 clamp to 640
// (finite, masked by A-bit=0 -> exact 0). Masks/list/write/finalize verbatim
// R19 (absmax 0.5).

#define F_DIM 640
#define C_DIM 256
#define SLAB_STRIDE (641 * 256)   // floats per king slab
#define NKING 64
#define NBAND 7                   // 7 bands x 96 rows
#define LCAP 256                  // list capacity per king
#define NC_MAX 64                 // max 64-entry chunks (nent <= 4096)

// ws layout (bytes)
#define WS_MASK_OFF 0                        // 1024*10*8 = 80 KB
#define WS_PART_OFF 81920                    // 14*1024*256*4 = 14.7 MB
#define WS_NEED (WS_PART_OFF + NBAND * 2 * 1024 * 256 * 4)

typedef float  f32x4  __attribute__((ext_vector_type(4)));
typedef short  bf16x8 __attribute__((ext_vector_type(8)));

__device__ __forceinline__ void gl_lds16(const float* g, unsigned* l) {
    // 16B-wide async global->LDS DMA; LDS dest = uniform base + lane*16.
    __builtin_amdgcn_global_load_lds(
        (const __attribute__((address_space(1))) void*)g,
        (__attribute__((address_space(3))) void*)l, 16, 0, 0);
}

__device__ __forceinline__ bf16x8 mk_a8(unsigned m32, int g) {
    // A-frag: 8 bf16 0/1 from byte g of a 32-bit window mask (k = g*8 + j)
    const unsigned by = (m32 >> (g * 8)) & 0xFFu;
    union { unsigned u[4]; bf16x8 v; } r;
    #pragma unroll
    for (int i = 0; i < 4; ++i)
        r.u[i] = (((by >> (2 * i)) & 1u) ? 0x3F80u : 0u) |
                 (((by >> (2 * i + 1)) & 1u) ? 0x3F800000u : 0u);
    return r.v;
}

__global__ __launch_bounds__(256)
void pack_masks(const int* __restrict__ pieces,          // (B,640) int32 0/1
                unsigned long long* __restrict__ mask,   // (B,10)
                int nwords)                              // B*10
{
    const int gw = blockIdx.x * 4 + (threadIdx.x >> 6);
    const int lane = threadIdx.x & 63;
    if (gw >= nwords) return;
    const int v = pieces[(size_t)gw * 64 + lane];
    const unsigned long long m = __ballot(v != 0);
    if (lane == 0) mask[gw] = m;
}

__global__ __launch_bounds__(512, 4)
void halfkp_dma(const float* __restrict__ W,                 // (64,641,256)
                const unsigned long long* __restrict__ mask, // (B,10)
                const int* __restrict__ kings,               // flat (B*2)
                float* __restrict__ partial,                 // (14,B,256)
                int nent)
{
    const int k  = blockIdx.x;
    const int bd = blockIdx.y;               // band 0..6
    const int t  = threadIdx.x;
    const int wv = t >> 6, lane = t & 63;
    const int mt = wv & 1;                   // M-tile slot (tiles mt, mt+2)
    const int cg = wv >> 1;                  // col-group 0..3 (64 cols)
    const int li = lane & 15, g = lane >> 4;

    __shared__ unsigned s_Wf[32 * 256];      // 32 KB: one 32-row f32 sub-window
    __shared__ int s_ent[LCAP];
    __shared__ int s_cb[NC_MAX + 1];
    __shared__ unsigned s_m32[64][3];        // band's 3 window masks per row
    __shared__ int s_nk;

    const float* __restrict__ Wk = W + (size_t)k * SLAB_STRIDE;

    // stage(ws): each wave DMAs 4 rows (1 KB each) of sub-window ws.
    // Global source pre-swizzled: lane' = lane ^ ((wr>>3)&3)<<2.
    #define STAGE(ws_)                                                        \
        {                                                                     \
            _Pragma("unroll")                                                 \
            for (int q = 0; q < 4; ++q) {                                     \
                const int wr = wv * 4 + q;                                    \
                const int frow = min(bd * 96 + (ws_) * 32 + wr, F_DIM);       \
                const int lsw = lane ^ (((wr >> 3) & 3) << 2);                \
                gl_lds16(Wk + (size_t)frow * C_DIM + lsw * 4,                 \
                         &s_Wf[wr * 256]);                                    \
            }                                                                 \
        }

    // ---- A: issue sub-window 0 DMA (flies under list+mask build) ----
    STAGE(0)

    // ---- B: in-block list build (R10-verified stable compaction) ----
    {
        const int NC = nent >> 6;            // 64-entry chunks
        const int nit = NC >> 3;             // chunks per wave (8 waves)
        unsigned long long mm[8];
        #pragma unroll
        for (int it = 0; it < 8; ++it) {
            if (it < nit) {
                const int c = wv + (it << 3);
                const int kk = kings[(c << 6) + lane];
                mm[it] = __ballot(kk == k);
                if (lane == 0) s_cb[c] = (int)__popcll(mm[it]);
            }
        }
        __syncthreads();
        if (t == 0) {
            int s = 0;
            for (int c = 0; c < NC; ++c) { const int v = s_cb[c]; s_cb[c] = s; s += v; }
            s_nk = min(s, LCAP);
        }
        __syncthreads();
        const unsigned long long lt = (1ull << lane) - 1ull;
        #pragma unroll
        for (int it = 0; it < 8; ++it) {
            if (it < nit) {
                const int c = wv + (it << 3);
                if ((mm[it] >> lane) & 1ull) {
                    const int pos = s_cb[c] + (int)__popcll(mm[it] & lt);
                    if (pos < LCAP) s_ent[pos] = (c << 6) + lane;
                }
            }
        }
    }
    __syncthreads();
    const int n_k = s_nk;

    // ---- C: chunk-0 masks (3 windows of this band) ----
    {
        const int ncc0 = min(n_k, 64);
        for (int idx = t; idx < 64 * 3; idx += 512) {
            const int row = idx & 63, ksl = idx >> 6;
            const int ksg = bd * 3 + ksl;    // global window 0..20
            const int id = (row < ncc0) ? s_ent[row] : -1;
            unsigned v = 0;
            if (id >= 0) {
                if (ksg < 20) {
                    const unsigned long long mw = mask[(size_t)(id >> 1) * 10 + (ksg >> 1)];
                    v = (unsigned)(mw >> ((ksg & 1) * 32));
                } else {
                    v = 1u;                  // window 20: only row 640 live
                }
            }
            s_m32[row][ksl] = v;
        }
    }

    for (int mb = 0; mb < n_k; mb += 64) {    // realistically one iteration
        const int ncc = min(n_k - mb, 64);

        if (mb > 0) {                         // rare: rebuild masks + restage w0
            __syncthreads();
            for (int idx = t; idx < 64 * 3; idx += 512) {
                const int row = idx & 63, ksl = idx >> 6;
                const int ksg = bd * 3 + ksl;
                const int id = (row < ncc) ? s_ent[mb + row] : -1;
                unsigned v = 0;
                if (id >= 0) {
                    if (ksg < 20) {
                        const unsigned long long mw = mask[(size_t)(id >> 1) * 10 + (ksg >> 1)];
                        v = (unsigned)(mw >> ((ksg & 1) * 32));
                    } else {
                        v = 1u;
                    }
                }
                s_m32[row][ksl] = v;
            }
            STAGE(0)
        }
        __syncthreads();                      // drain DMA + masks ready

        f32x4 acc[2][4];
        #pragma unroll
        for (int a = 0; a < 2; ++a)
            #pragma unroll
            for (int nt = 0; nt < 4; ++nt) acc[a][nt] = (f32x4){0.f, 0.f, 0.f, 0.f};

        #pragma unroll
        for (int ws = 0; ws < 3; ++ws) {
            if (ws > 0) {
                __syncthreads();              // all waves done reading s_Wf
                STAGE(ws)
                __syncthreads();              // drain DMA (vmcnt before barrier)
            }
            // ---- MFMA on this 32-row window; bf16 cvt in read path ----
            #pragma unroll
            for (int tb = 0; tb < 2; ++tb) {
                const int tile = tb * 2 + mt;
                if (tile * 16 < ncc) {
                    const bf16x8 af = mk_a8(s_m32[tile * 16 + li][ws], g);
                    #pragma unroll
                    for (int nt = 0; nt < 4; ++nt) {
                        const int col = cg * 64 + nt * 16 + li;
                        const int colsw = col ^ (g << 4);   // undo stage swizzle
                        union { unsigned u[4]; bf16x8 v; } bb;
                        #pragma unroll
                        for (int jj = 0; jj < 4; ++jj) {
                            const int rr = g * 8 + 2 * jj;
                            const float lo = __uint_as_float(s_Wf[rr * 256 + colsw]);
                            const float hi = __uint_as_float(s_Wf[(rr + 1) * 256 + colsw]);
                            asm("v_cvt_pk_bf16_f32 %0, %1, %2"
                                : "=v"(bb.u[jj]) : "v"(lo), "v"(hi));
                        }
                        acc[tb][nt] = __builtin_amdgcn_mfma_f32_16x16x32_bf16(
                            af, bb.v, acc[tb][nt], 0, 0, 0);
                    }
                }
            }
        }

        // ---- write band-partials (slot = bd*2 + persp), D-map m89-verified ----
        #pragma unroll
        for (int tb = 0; tb < 2; ++tb) {
            const int tile = tb * 2 + mt;
            if (tile * 16 < ncc) {
                #pragma unroll
                for (int i = 0; i < 4; ++i) {
                    const int r = tile * 16 + 4 * g + i;
                    if (r < ncc) {
                        const int id = s_ent[mb + r];
                        float* dst = &partial[(((size_t)(bd * 2 + (id & 1))) * 1024
                                              + (id >> 1)) * C_DIM + cg * 64];
                        #pragma unroll
                        for (int nt = 0; nt < 4; ++nt)
                            dst[nt * 16 + li] = acc[tb][nt][i];
                    }
                }
            }
        }
    }
    #undef STAGE
}

__global__ __launch_bounds__(256)
void finalize(const float* __restrict__ partial,   // (14,B,256)
              const float* __restrict__ bias,
              float* __restrict__ out)
{
    const int i = blockIdx.x * 256 + threadIdx.x;    // float4 index, B*64 total
    float4 s = ((const float4*)bias)[i & 63];
    #pragma unroll
    for (int sl = 0; sl < NBAND * 2; ++sl) {         // fixed order: deterministic
        const float4 p = ((const float4*)partial)[(size_t)sl * 1024 * 64 + i];
        s.x += p.x; s.y += p.y; s.z += p.z; s.w += p.w;
    }
    ((float4*)out)[i] = s;
}

// ---- fallback (R3 path) if ws is too small ----
__global__ __launch_bounds__(256)
void halfkp_fallback(const int* __restrict__ pieces, const int* __restrict__ kings,
                     const float* __restrict__ W, const float* __restrict__ bias,
                     float* __restrict__ out)
{
    const int b = blockIdx.x;
    const int c = threadIdx.x;
    const int lane = c & 63;
    const int k0 = kings[2 * b + 0];
    const int k1 = kings[2 * b + 1];
    const float* W0 = W + (size_t)k0 * SLAB_STRIDE + c;
    const float* W1 = W + (size_t)k1 * SLAB_STRIDE + c;
    float acc = bias[c] + W0[640 * 256] + W1[640 * 256];
    const int* pi = pieces + (size_t)b * F_DIM;
    #pragma unroll
    for (int ch = 0; ch < 10; ++ch) {
        int v = pi[ch * 64 + lane];
        unsigned long long m = __ballot(v != 0);
        const float* b0 = W0 + ch * 64 * 256;
        const float* b1 = W1 + ch * 64 * 256;
        while (m) {
            const int f = __builtin_ctzll(m);
            m &= m - 1;
            acc += b0[f * 256] + b1[f * 256];
        }
    }
    out[(size_t)b * C_DIM + c] = acc;
}

extern "C" void kernel_launch(void* const* d_in, const int* in_sizes, int n_in,
                              void* d_out, int out_size, void* d_ws, size_t ws_size,
                              hipStream_t stream) {
    const int* pieces = (const int*)d_in[0];   // (1024, 640) int32 bools
    const int* kings  = (const int*)d_in[1];   // (1024, 2) int32
    const float* W    = (const float*)d_in[2]; // (64, 641, 256) f32
    const float* bias = (const float*)d_in[3]; // (256,) f32
    float* out        = (float*)d_out;         // (1024, 256) f32

    const int B = in_sizes[1] / 2;             // 1024
    const int nent = 2 * B;
    const int nwords = B * 10;

    if (ws_size < (size_t)WS_NEED) {
        halfkp_fallback<<<dim3(B), dim3(C_DIM), 0, stream>>>(pieces, kings, W, bias, out);
        return;
    }

    unsigned long long* mask = (unsigned long long*)((char*)d_ws + WS_MASK_OFF);
    float* part = (float*)((char*)d_ws + WS_PART_OFF);

    pack_masks<<<dim3((nwords + 3) / 4), dim3(256), 0, stream>>>(pieces, mask, nwords);
    halfkp_dma<<<dim3(NKING, NBAND), dim3(512), 0, stream>>>(W, mask, kings, part, nent);
    finalize<<<dim3(B * 64 / 256), dim3(256), 0, stream>>>(part, bias, out);
}